// Round 3
// baseline (632.334 us; speedup 1.0000x reference)
//
#include <hip/hip_runtime.h>

#define N_NODES 100000
#define N_EDGES 1600000
#define FEATS 48
#define BUCKET 512
#define BUCKET_SHIFT 9
#define NBUCK ((N_NODES + BUCKET - 1) / BUCKET)   /* 196 */
#define EPB 4096                                  /* edges per partition block */

// ---------------- radix path ----------------

// Partition edges into NBUCK buckets by dst>>9. Per-block LDS histogram +
// one bulk reservation per (block,bucket): 77K global atomics total, and
// writes cluster into contiguous ~84B runs per bucket per block.
__global__ __launch_bounds__(256) void partition_kernel(
    const int* __restrict__ src, const int* __restrict__ dst,
    int* __restrict__ gcur, int* __restrict__ packed, int cap) {
    __shared__ int hist[NBUCK];
    __shared__ int base[NBUCK];
    int tid = threadIdx.x;
    for (int i = tid; i < NBUCK; i += 256) hist[i] = 0;
    __syncthreads();
    int e0 = blockIdx.x * EPB;
    int ks[16], pk[16];
#pragma unroll
    for (int i = 0; i < 16; ++i) {
        int e = e0 + i * 256 + tid;
        if (e < N_EDGES) {
            int d = dst[e], s = src[e];
            ks[i] = d >> BUCKET_SHIFT;
            pk[i] = (s << BUCKET_SHIFT) | (d & (BUCKET - 1));
            atomicAdd(&hist[ks[i]], 1);
        } else ks[i] = -1;
    }
    __syncthreads();
    for (int i = tid; i < NBUCK; i += 256) {
        int h = hist[i];
        base[i] = (h > 0) ? atomicAdd(&gcur[i], h) : 0;
    }
    __syncthreads();
    for (int i = tid; i < NBUCK; i += 256) hist[i] = 0;  // reuse as cursor
    __syncthreads();
#pragma unroll
    for (int i = 0; i < 16; ++i) {
        int k = ks[i];
        if (k >= 0) {
            int pos = base[k] + atomicAdd(&hist[k], 1);
            if (pos < cap) packed[(size_t)k * cap + pos] = pk[i];
        }
    }
}

// One block per bucket: LDS f32 accumulator [512][48] (98KB), edges read
// coalesced, per edge a 192B feature-row read + 48 LDS atomic adds.
// Fused mean + linear epilogue.
__global__ __launch_bounds__(512) void aggregate_kernel(
    const float* __restrict__ feature, const int* __restrict__ packed,
    const int* __restrict__ gcur, const float* __restrict__ W,
    const float* __restrict__ bias, float* __restrict__ out, int cap) {
    __shared__ float accS[BUCKET][FEATS];
    __shared__ float degS[BUCKET];
    __shared__ float Wt[FEATS * FEATS];
    int tid = threadIdx.x;
    float* af = &accS[0][0];
    for (int i = tid; i < BUCKET * FEATS; i += 512) af[i] = 0.f;
    for (int i = tid; i < BUCKET; i += 512) degS[i] = 0.f;
    for (int i = tid; i < FEATS * FEATS; i += 512) {
        int o = i / FEATS, f = i - o * FEATS;
        Wt[f * FEATS + o] = W[i];
    }
    __syncthreads();

    int bkt = blockIdx.x;
    int c = min(gcur[bkt], cap);
    const int* __restrict__ ep = packed + (size_t)bkt * cap;
    int wave = tid >> 6, lane = tid & 63;

    for (int chunk = wave * 64; chunk < c; chunk += 8 * 64) {
        int n = c - chunk; if (n > 64) n = 64;
        int pv = (lane < n) ? ep[chunk + lane] : 0;
        if (n == 64) {
#pragma unroll 16
            for (int j = 0; j < 64; ++j) {
                int pe = __shfl(pv, j);
                int s = pe >> BUCKET_SHIFT, ld = pe & (BUCKET - 1);
                if (lane < FEATS)      atomicAdd(&accS[ld][lane], feature[s * FEATS + lane]);
                else if (lane == FEATS) atomicAdd(&degS[ld], 1.0f);
            }
        } else {
            for (int j = 0; j < n; ++j) {
                int pe = __shfl(pv, j);
                int s = pe >> BUCKET_SHIFT, ld = pe & (BUCKET - 1);
                if (lane < FEATS)      atomicAdd(&accS[ld][lane], feature[s * FEATS + lane]);
                else if (lane == FEATS) atomicAdd(&degS[ld], 1.0f);
            }
        }
    }
    __syncthreads();

    int nbase = bkt * BUCKET;
    for (int nd = wave; nd < BUCKET; nd += 8) {
        int gn = nbase + nd;
        if (gn >= N_NODES) break;
        if (lane < FEATS) {
            float inv = 1.0f / fmaxf(degS[nd], 1.0f);
            float r = 0.f;
#pragma unroll
            for (int f = 0; f < FEATS; ++f)
                r += accS[nd][f] * Wt[f * FEATS + lane];   // accS broadcast, Wt conflict-free
            out[(size_t)gn * FEATS + lane] = bias[lane] + inv * r;
        }
    }
}

// ---------------- CSR fallback (R2) ----------------

__global__ void count_kernel(const int* __restrict__ dst, int* __restrict__ cnt) {
    int e = blockIdx.x * blockDim.x + threadIdx.x;
    if (e < N_EDGES) atomicAdd(&cnt[dst[e]], 1);
}

__global__ void offsets_kernel(const int* __restrict__ cnt, int* __restrict__ gcounter,
                               int* __restrict__ off, int* __restrict__ cur) {
    int n = blockIdx.x * blockDim.x + threadIdx.x;
    int lane = threadIdx.x & 63;
    int c = (n < N_NODES) ? cnt[n] : 0;
    int incl = c;
#pragma unroll
    for (int d = 1; d < 64; d <<= 1) {
        int v = __shfl_up(incl, d);
        if (lane >= d) incl += v;
    }
    int wtot = __shfl(incl, 63);
    int base = 0;
    if (lane == 63) base = atomicAdd(gcounter, wtot);
    base = __shfl(base, 63);
    int o = base + incl - c;
    if (n < N_NODES) { off[n] = o; cur[n] = o; }
}

__global__ void scatter_kernel(const int* __restrict__ src, const int* __restrict__ dst,
                               int* __restrict__ cur, int* __restrict__ eid) {
    int e = blockIdx.x * blockDim.x + threadIdx.x;
    if (e < N_EDGES) {
        int p = atomicAdd(&cur[dst[e]], 1);
        eid[p] = src[e];
    }
}

__global__ __launch_bounds__(256) void gather_kernel(
    const float* __restrict__ feature,
    const int* __restrict__ cnt, const int* __restrict__ off,
    const int* __restrict__ eid,
    const float* __restrict__ W, const float* __restrict__ b,
    float* __restrict__ out) {
    __shared__ float Wt[FEATS * FEATS];
    __shared__ float meanS[4][FEATS];
    int tid = threadIdx.x;
    for (int i = tid; i < FEATS * FEATS; i += 256) {
        int o = i / FEATS, f = i - o * FEATS;
        Wt[f * FEATS + o] = W[i];
    }
    __syncthreads();
    int wave = tid >> 6, lane = tid & 63;
    int n = blockIdx.x * 4 + wave;
    if (n >= N_NODES) return;
    int c = cnt[n];
    int o = off[n];
    if (lane < FEATS) {
        float acc = 0.f;
        int t = lane, i = 0;
        for (; i + 4 <= c; i += 4) {
            int s0 = eid[o + i], s1 = eid[o + i + 1], s2 = eid[o + i + 2], s3 = eid[o + i + 3];
            acc += feature[s0 * FEATS + t];
            acc += feature[s1 * FEATS + t];
            acc += feature[s2 * FEATS + t];
            acc += feature[s3 * FEATS + t];
        }
        for (; i < c; ++i) acc += feature[eid[o + i] * FEATS + t];
        meanS[wave][t] = acc / fmaxf((float)c, 1.0f);
        float r = b[t];
#pragma unroll
        for (int f = 0; f < FEATS; ++f) r += meanS[wave][f] * Wt[f * FEATS + t];
        out[n * FEATS + t] = r;
    }
}

extern "C" void kernel_launch(void* const* d_in, const int* in_sizes, int n_in,
                              void* d_out, int out_size, void* d_ws, size_t ws_size,
                              hipStream_t stream) {
    const float* feature = (const float*)d_in[0];
    const float* W       = (const float*)d_in[1];
    const float* b       = (const float*)d_in[2];
    const int*   src     = (const int*)d_in[3];
    const int*   dst     = (const int*)d_in[4];
    float* out = (float*)d_out;

    // radix path workspace: gcur[NBUCK] | packed[NBUCK*cap]
    size_t avail_ints = ws_size / sizeof(int);
    long long cap_ll = ((long long)avail_ints - NBUCK) / NBUCK;
    int cap = (cap_ll > 16384) ? 16384 : (int)cap_ll;
    cap &= ~63;
    // expected max bucket load ~8.5K (mean 8163, sigma 90); require >=9472
    if (cap >= 9472) {
        int* gcur = (int*)d_ws;
        int* packed = gcur + NBUCK;
        hipMemsetAsync(gcur, 0, NBUCK * sizeof(int), stream);
        int pb = (N_EDGES + EPB - 1) / EPB;
        partition_kernel<<<pb, 256, 0, stream>>>(src, dst, gcur, packed, cap);
        aggregate_kernel<<<NBUCK, 512, 0, stream>>>(feature, packed, gcur, W, b, out, cap);
        return;
    }

    // CSR fallback: cnt[N] | gcounter[1] | off[N] | cur[N] | eid[E]
    const size_t needed = ((size_t)3 * N_NODES + 1 + N_EDGES) * sizeof(int);
    if (ws_size >= needed) {
        int* I = (int*)d_ws;
        int* cnt = I;
        int* gcounter = I + N_NODES;
        int* off = I + N_NODES + 1;
        int* cur = off + N_NODES;
        int* eid = cur + N_NODES;
        hipMemsetAsync(cnt, 0, (size_t)(N_NODES + 1) * sizeof(int), stream);
        int eb = (N_EDGES + 255) / 256;
        count_kernel<<<eb, 256, 0, stream>>>(dst, cnt);
        int nb = (N_NODES + 255) / 256;
        offsets_kernel<<<nb, 256, 0, stream>>>(cnt, gcounter, off, cur);
        scatter_kernel<<<eb, 256, 0, stream>>>(src, dst, cur, eid);
        gather_kernel<<<(N_NODES + 3) / 4, 256, 0, stream>>>(feature, cnt, off, eid, W, b, out);
    }
}

// Round 5
// 556.004 us; speedup vs baseline: 1.1373x; 1.1373x over previous
//
#include <hip/hip_runtime.h>

#define N_NODES 100000
#define N_EDGES 1600000
#define FEATS 48
#define BSH 6                       /* 64-node buckets */
#define BUCK 64
#define NB ((N_NODES + BUCK - 1) / BUCK)   /* 1563 */
#define EPB 8192                    /* edges per partition block */
#define PBLK ((N_EDGES + EPB - 1) / EPB)   /* 196 */

// ---- pass 1: per-bucket edge counts (LDS hist -> global atomics) ----
__global__ __launch_bounds__(256) void bucket_count(const int* __restrict__ dst,
                                                    int* __restrict__ cnt) {
    __shared__ int hist[NB];
    int tid = threadIdx.x;
    for (int i = tid; i < NB; i += 256) hist[i] = 0;
    __syncthreads();
    int e0 = blockIdx.x * EPB;
#pragma unroll
    for (int i = 0; i < EPB / 256; ++i) {
        int e = e0 + i * 256 + tid;
        if (e < N_EDGES) atomicAdd(&hist[dst[e] >> BSH], 1);
    }
    __syncthreads();
    for (int i = tid; i < NB; i += 256)
        if (hist[i]) atomicAdd(&cnt[i], hist[i]);
}

// ---- pass 2: exclusive scan of cnt[NB] (single block) ----
__global__ __launch_bounds__(256) void bucket_scan(const int* __restrict__ cnt,
                                                   int* __restrict__ base,
                                                   int* __restrict__ cur) {
    __shared__ int warr[256];
    const int PER = (NB + 255) / 256;  // 7
    int t = threadIdx.x;
    int v[7], s = 0;
#pragma unroll
    for (int j = 0; j < PER; ++j) {
        int i = t * PER + j;
        v[j] = (i < NB) ? cnt[i] : 0;
        s += v[j];
    }
    warr[t] = s;
    __syncthreads();
    for (int d = 1; d < 256; d <<= 1) {
        int x = (t >= d) ? warr[t - d] : 0;
        __syncthreads();
        warr[t] += x;
        __syncthreads();
    }
    int excl = warr[t] - s;
#pragma unroll
    for (int j = 0; j < PER; ++j) {
        int i = t * PER + j;
        if (i < NB) { base[i] = excl; cur[i] = excl; }
        excl += v[j];
    }
}

// ---- pass 3: scatter packed (src<<6 | dst&63) into exact bucket segments ----
__global__ __launch_bounds__(256) void bucket_scatter(const int* __restrict__ src,
                                                      const int* __restrict__ dst,
                                                      int* __restrict__ cur,
                                                      int* __restrict__ packed) {
    __shared__ int hist[NB];
    __shared__ int lbase[NB];
    int tid = threadIdx.x;
    for (int i = tid; i < NB; i += 256) hist[i] = 0;
    __syncthreads();
    int e0 = blockIdx.x * EPB;
#pragma unroll
    for (int i = 0; i < EPB / 256; ++i) {
        int e = e0 + i * 256 + tid;
        if (e < N_EDGES) atomicAdd(&hist[dst[e] >> BSH], 1);
    }
    __syncthreads();
    for (int i = tid; i < NB; i += 256) {
        int h = hist[i];
        lbase[i] = h ? atomicAdd(&cur[i], h) : 0;
        hist[i] = 0;   // reuse as local cursor
    }
    __syncthreads();
#pragma unroll
    for (int i = 0; i < EPB / 256; ++i) {
        int e = e0 + i * 256 + tid;
        if (e < N_EDGES) {
            int d = dst[e], s = src[e];
            int k = d >> BSH;
            int pos = lbase[k] + atomicAdd(&hist[k], 1);
            packed[pos] = (s << BSH) | (d & (BUCK - 1));
        }
    }
}

// ---- pass 4: one block per 64-node bucket; 4 edges in flight per wave ----
// BUGFIX vs R4: __shfl must be executed by ALL lanes (uniform exec) — on CDNA,
// ds_bpermute reads from exec-masked-off lanes return 0, so a group-divergent
// `if (idx < n)` around the shuffle silently corrupted tail chunks.
__global__ __launch_bounds__(256) void aggregate_kernel(
    const float4* __restrict__ feat4, const int* __restrict__ packed,
    const int* __restrict__ base, const int* __restrict__ cnt,
    const float* __restrict__ W, const float* __restrict__ bias,
    float* __restrict__ out) {
    __shared__ float accS[BUCK][FEATS];   // 12.3 KB
    __shared__ float degS[BUCK];
    __shared__ float Wt[FEATS * FEATS];   // 9.2 KB, Wt[f*48+o] = W[o*48+f]
    int tid = threadIdx.x;
    float* af = &accS[0][0];
    for (int i = tid; i < BUCK * FEATS; i += 256) af[i] = 0.f;
    if (tid < BUCK) degS[tid] = 0.f;
    for (int i = tid; i < FEATS * FEATS; i += 256) {
        int o = i / FEATS, f = i - o * FEATS;
        Wt[f * FEATS + o] = W[i];
    }
    __syncthreads();

    int k = blockIdx.x;
    int c = cnt[k];
    const int* __restrict__ ep = packed + base[k];
    int wave = tid >> 6, lane = tid & 63;
    int grp = lane >> 4, sub = lane & 15;   // 4 edge-groups of 16 lanes

    for (int chunk = wave * 64; chunk < c; chunk += 256) {
        int n = c - chunk; if (n > 64) n = 64;
        int pv = (lane < n) ? ep[chunk + lane] : 0;
        if (n == 64) {
#pragma unroll 4
            for (int j = 0; j < 16; ++j) {
                int pe = __shfl(pv, j * 4 + grp);   // all lanes active
                int s = pe >> BSH, ld = pe & (BUCK - 1);
                if (sub < 12) {
                    float4 v = feat4[(size_t)s * 12 + sub];
                    atomicAdd(&accS[ld][sub * 4 + 0], v.x);
                    atomicAdd(&accS[ld][sub * 4 + 1], v.y);
                    atomicAdd(&accS[ld][sub * 4 + 2], v.z);
                    atomicAdd(&accS[ld][sub * 4 + 3], v.w);
                } else if (sub == 12) {
                    atomicAdd(&degS[ld], 1.0f);
                }
            }
        } else {
            for (int j = 0; j < 16; ++j) {
                int idx = j * 4 + grp;
                int pe = __shfl(pv, idx);           // UNCONDITIONAL: uniform exec
                bool valid = (idx < n);
                int s = pe >> BSH, ld = pe & (BUCK - 1);
                if (valid) {
                    if (sub < 12) {
                        float4 v = feat4[(size_t)s * 12 + sub];
                        atomicAdd(&accS[ld][sub * 4 + 0], v.x);
                        atomicAdd(&accS[ld][sub * 4 + 1], v.y);
                        atomicAdd(&accS[ld][sub * 4 + 2], v.z);
                        atomicAdd(&accS[ld][sub * 4 + 3], v.w);
                    } else if (sub == 12) {
                        atomicAdd(&degS[ld], 1.0f);
                    }
                }
            }
        }
    }
    __syncthreads();

    int nbase = k * BUCK;
    float bv = (lane < FEATS) ? bias[lane] : 0.f;
    for (int nd = wave; nd < BUCK; nd += 4) {
        int gn = nbase + nd;
        if (gn >= N_NODES) break;
        if (lane < FEATS) {
            float inv = 1.0f / fmaxf(degS[nd], 1.0f);
            float r = 0.f;
#pragma unroll
            for (int f = 0; f < FEATS; ++f)
                r += accS[nd][f] * Wt[f * FEATS + lane];  // accS broadcast, Wt 2-way max
            out[(size_t)gn * FEATS + lane] = bv + inv * r;
        }
    }
}

// ---------------- CSR fallback (R2, known-good 322us) ----------------

__global__ void count_kernel(const int* __restrict__ dst, int* __restrict__ cnt) {
    int e = blockIdx.x * blockDim.x + threadIdx.x;
    if (e < N_EDGES) atomicAdd(&cnt[dst[e]], 1);
}

__global__ void offsets_kernel(const int* __restrict__ cnt, int* __restrict__ gcounter,
                               int* __restrict__ off, int* __restrict__ cur) {
    int n = blockIdx.x * blockDim.x + threadIdx.x;
    int lane = threadIdx.x & 63;
    int c = (n < N_NODES) ? cnt[n] : 0;
    int incl = c;
#pragma unroll
    for (int d = 1; d < 64; d <<= 1) {
        int v = __shfl_up(incl, d);
        if (lane >= d) incl += v;
    }
    int wtot = __shfl(incl, 63);
    int b0 = 0;
    if (lane == 63) b0 = atomicAdd(gcounter, wtot);
    b0 = __shfl(b0, 63);
    int o = b0 + incl - c;
    if (n < N_NODES) { off[n] = o; cur[n] = o; }
}

__global__ void scatter_kernel(const int* __restrict__ src, const int* __restrict__ dst,
                               int* __restrict__ cur, int* __restrict__ eid) {
    int e = blockIdx.x * blockDim.x + threadIdx.x;
    if (e < N_EDGES) {
        int p = atomicAdd(&cur[dst[e]], 1);
        eid[p] = src[e];
    }
}

__global__ __launch_bounds__(256) void gather_kernel(
    const float* __restrict__ feature,
    const int* __restrict__ cnt, const int* __restrict__ off,
    const int* __restrict__ eid,
    const float* __restrict__ W, const float* __restrict__ b,
    float* __restrict__ out) {
    __shared__ float Wt[FEATS * FEATS];
    __shared__ float meanS[4][FEATS];
    int tid = threadIdx.x;
    for (int i = tid; i < FEATS * FEATS; i += 256) {
        int o = i / FEATS, f = i - o * FEATS;
        Wt[f * FEATS + o] = W[i];
    }
    __syncthreads();
    int wave = tid >> 6, lane = tid & 63;
    int n = blockIdx.x * 4 + wave;
    if (n >= N_NODES) return;
    int c = cnt[n];
    int o = off[n];
    if (lane < FEATS) {
        float acc = 0.f;
        int t = lane, i = 0;
        for (; i + 4 <= c; i += 4) {
            int s0 = eid[o + i], s1 = eid[o + i + 1], s2 = eid[o + i + 2], s3 = eid[o + i + 3];
            acc += feature[s0 * FEATS + t];
            acc += feature[s1 * FEATS + t];
            acc += feature[s2 * FEATS + t];
            acc += feature[s3 * FEATS + t];
        }
        for (; i < c; ++i) acc += feature[eid[o + i] * FEATS + t];
        meanS[wave][t] = acc / fmaxf((float)c, 1.0f);
        float r = b[t];
#pragma unroll
        for (int f = 0; f < FEATS; ++f) r += meanS[wave][f] * Wt[f * FEATS + t];
        out[n * FEATS + t] = r;
    }
}

extern "C" void kernel_launch(void* const* d_in, const int* in_sizes, int n_in,
                              void* d_out, int out_size, void* d_ws, size_t ws_size,
                              hipStream_t stream) {
    const float* feature = (const float*)d_in[0];
    const float* W       = (const float*)d_in[1];
    const float* b       = (const float*)d_in[2];
    const int*   src     = (const int*)d_in[3];
    const int*   dst     = (const int*)d_in[4];
    float* out = (float*)d_out;

    // radix path ws: cnt[NB] | base[NB] | cur[NB] | packed[N_EDGES]
    const size_t need_radix = ((size_t)3 * NB + N_EDGES) * sizeof(int);
    if (ws_size >= need_radix) {
        int* I = (int*)d_ws;
        int* cnt    = I;
        int* base   = I + NB;
        int* cur    = I + 2 * NB;
        int* packed = I + 3 * NB;
        hipMemsetAsync(cnt, 0, NB * sizeof(int), stream);
        bucket_count  <<<PBLK, 256, 0, stream>>>(dst, cnt);
        bucket_scan   <<<1, 256, 0, stream>>>(cnt, base, cur);
        bucket_scatter<<<PBLK, 256, 0, stream>>>(src, dst, cur, packed);
        aggregate_kernel<<<NB, 256, 0, stream>>>((const float4*)feature, packed,
                                                 base, cnt, W, b, out);
        return;
    }

    // CSR fallback
    const size_t need_csr = ((size_t)3 * N_NODES + 1 + N_EDGES) * sizeof(int);
    if (ws_size >= need_csr) {
        int* I = (int*)d_ws;
        int* cnt = I;
        int* gcounter = I + N_NODES;
        int* off = I + N_NODES + 1;
        int* cur = off + N_NODES;
        int* eid = cur + N_NODES;
        hipMemsetAsync(cnt, 0, (size_t)(N_NODES + 1) * sizeof(int), stream);
        int eb = (N_EDGES + 255) / 256;
        count_kernel<<<eb, 256, 0, stream>>>(dst, cnt);
        int nb = (N_NODES + 255) / 256;
        offsets_kernel<<<nb, 256, 0, stream>>>(cnt, gcounter, off, cur);
        scatter_kernel<<<eb, 256, 0, stream>>>(src, dst, cur, eid);
        gather_kernel<<<(N_NODES + 3) / 4, 256, 0, stream>>>(feature, cnt, off, eid, W, b, out);
    }
}